// Round 1
// baseline (193.441 us; speedup 1.0000x reference)
//
#include <hip/hip_runtime.h>
#include <math.h>

#define Bn 8
#define Hn 256
#define Wn 256

// Load a 3x6 window (rows h-1..h+1, cols w0-1..w0+4) from a 256x256 plane,
// zero-padded at borders. w0 is a multiple of 4 so the middle 4 cols are one
// aligned float4.
__device__ __forceinline__ void load_win6(const float* __restrict__ plane,
                                          int h, int w0, float win[3][6]) {
#pragma unroll
  for (int r = 0; r < 3; ++r) {
    int hh = h - 1 + r;
    bool okh = (unsigned)hh < (unsigned)Hn;
    const float* row = plane + hh * Wn;
    if (okh) {
      float4 mid = *(const float4*)(row + w0);
      win[r][0] = (w0 > 0) ? row[w0 - 1] : 0.f;
      win[r][1] = mid.x; win[r][2] = mid.y; win[r][3] = mid.z; win[r][4] = mid.w;
      win[r][5] = (w0 + 4 < Wn) ? row[w0 + 4] : 0.f;
    } else {
#pragma unroll
      for (int c = 0; c < 6; ++c) win[r][c] = 0.f;
    }
  }
}

// Kernel A: fused per-neighbor conv1(2->64,3x3)+ReLU -> conv2(64->1,1x1)
// -> sigmoid -> gate neighbor. Writes "combined" (B,7,H,W) into ws.
// Each thread computes 4 consecutive pixels (same row).
// LDS weight layout per (n,c): 20 floats = [wBase(9), wCheck(9), b1, W2],
// with channel roles pre-swapped for n>=3 so the inner loop is uniform.
__global__ __launch_bounds__(256) void sim_kernel(
    const float* __restrict__ x,   // (8,7,256,256)
    const float* __restrict__ W1,  // (6,64,2,3,3)
    const float* __restrict__ b1,  // (6,64)
    const float* __restrict__ W2,  // (6,1,64,1,1)
    const float* __restrict__ b2,  // (6,1)
    float* __restrict__ comb)      // (8,7,256,256)
{
  __shared__ float4 sw4[6 * 64 * 5];
  for (int t = threadIdx.x; t < 6 * 64 * 5; t += 256) {
    int nc = t / 5, j = t - nc * 5;
    int n = nc >> 6;
    float v[4];
#pragma unroll
    for (int e = 0; e < 4; ++e) {
      int kk = 4 * j + e;  // 0..19
      float val;
      if (kk < 18) {
        int i = kk / 9, k = kk - i * 9;
        // slot [0..8] must multiply BASE. For n<3 pair=[base,check] -> src i.
        // For n>=3 pair=[check,base] -> base weight is src channel 1 -> 1-i.
        int isrc = (n < 3) ? i : 1 - i;
        val = W1[nc * 18 + isrc * 9 + k];
      } else if (kk == 18) {
        val = b1[nc];
      } else {
        val = W2[nc];
      }
      v[e] = val;
    }
    sw4[t] = make_float4(v[0], v[1], v[2], v[3]);
  }
  __syncthreads();

  int idx = blockIdx.x * 256 + threadIdx.x;  // over B*H*W/4 = 131072
  int w0 = (idx & 63) << 2;
  int h  = (idx >> 6) & (Hn - 1);
  int b  = idx >> 14;

  const float* xb = x + (size_t)b * 7 * Hn * Wn;
  float* cb = comb + (size_t)b * 7 * Hn * Wn;

  float bwin[3][6];
  load_win6(xb + 3 * Hn * Wn, h, w0, bwin);

  // combined channel 3 = base (center taps)
  *(float4*)(cb + 3 * Hn * Wn + h * Wn + w0) =
      make_float4(bwin[1][1], bwin[1][2], bwin[1][3], bwin[1][4]);

  for (int n = 0; n < 6; ++n) {
    int cc = (n < 3) ? n : n + 1;
    float cwin[3][6];
    load_win6(xb + (size_t)cc * Hn * Wn, h, w0, cwin);

    float s0 = 0.f, s1 = 0.f, s2 = 0.f, s3 = 0.f;
    const float4* wb = sw4 + n * 64 * 5;
#pragma unroll 2
    for (int c = 0; c < 64; ++c) {
      float wv[20];
      float4* wvp = (float4*)wv;
      wvp[0] = wb[c * 5 + 0];
      wvp[1] = wb[c * 5 + 1];
      wvp[2] = wb[c * 5 + 2];
      wvp[3] = wb[c * 5 + 3];
      wvp[4] = wb[c * 5 + 4];
      float a0 = wv[18], a1 = wv[18], a2 = wv[18], a3 = wv[18];
#pragma unroll
      for (int dy = 0; dy < 3; ++dy) {
#pragma unroll
        for (int dx = 0; dx < 3; ++dx) {
          float wbv = wv[dy * 3 + dx];
          float wcv = wv[9 + dy * 3 + dx];
          a0 = fmaf(wbv, bwin[dy][0 + dx], a0);
          a1 = fmaf(wbv, bwin[dy][1 + dx], a1);
          a2 = fmaf(wbv, bwin[dy][2 + dx], a2);
          a3 = fmaf(wbv, bwin[dy][3 + dx], a3);
          a0 = fmaf(wcv, cwin[dy][0 + dx], a0);
          a1 = fmaf(wcv, cwin[dy][1 + dx], a1);
          a2 = fmaf(wcv, cwin[dy][2 + dx], a2);
          a3 = fmaf(wcv, cwin[dy][3 + dx], a3);
        }
      }
      float w2v = wv[19];
      s0 = fmaf(w2v, fmaxf(a0, 0.f), s0);
      s1 = fmaf(w2v, fmaxf(a1, 0.f), s1);
      s2 = fmaf(w2v, fmaxf(a2, 0.f), s2);
      s3 = fmaf(w2v, fmaxf(a3, 0.f), s3);
    }
    float bb = b2[n];
    float g0 = 1.f / (1.f + expf(-(s0 + bb)));
    float g1 = 1.f / (1.f + expf(-(s1 + bb)));
    float g2 = 1.f / (1.f + expf(-(s2 + bb)));
    float g3 = 1.f / (1.f + expf(-(s3 + bb)));
    *(float4*)(cb + (size_t)cc * Hn * Wn + h * Wn + w0) =
        make_float4(g0 * cwin[1][1], g1 * cwin[1][2],
                    g2 * cwin[1][3], g3 * cwin[1][4]);
  }
}

// Kernel B: final mixing conv (7->7, 3x3, SAME). 4 pixels per thread.
__global__ __launch_bounds__(256) void mix_kernel(
    const float* __restrict__ comb,  // (8,7,256,256)
    const float* __restrict__ Wm,    // (7,7,3,3)
    const float* __restrict__ bm,    // (7,)
    float* __restrict__ out)         // (8,7,256,256)
{
  __shared__ float sW[7 * 7 * 12];  // [oc][ic][12], taps in [0..8]
  __shared__ float sb[7];
  for (int t = threadIdx.x; t < 7 * 7 * 9; t += 256) {
    int oi = t / 9, k = t - oi * 9;
    sW[oi * 12 + k] = Wm[t];
  }
  if (threadIdx.x < 7) sb[threadIdx.x] = bm[threadIdx.x];
  __syncthreads();

  int idx = blockIdx.x * 256 + threadIdx.x;
  int w0 = (idx & 63) << 2;
  int h  = (idx >> 6) & (Hn - 1);
  int b  = idx >> 14;
  const float* cbase = comb + (size_t)b * 7 * Hn * Wn;

  float acc[7][4];
#pragma unroll
  for (int oc = 0; oc < 7; ++oc) {
    float bv = sb[oc];
#pragma unroll
    for (int p = 0; p < 4; ++p) acc[oc][p] = bv;
  }

  for (int ic = 0; ic < 7; ++ic) {
    float cwin[3][6];
    load_win6(cbase + (size_t)ic * Hn * Wn, h, w0, cwin);
#pragma unroll
    for (int oc = 0; oc < 7; ++oc) {
      const float* wp = &sW[(oc * 7 + ic) * 12];
      float wv[9];
      *(float4*)&wv[0] = *(const float4*)(wp);
      float4 t2 = *(const float4*)(wp + 4);
      wv[4] = t2.x; wv[5] = t2.y; wv[6] = t2.z; wv[7] = t2.w;
      wv[8] = wp[8];
#pragma unroll
      for (int dy = 0; dy < 3; ++dy) {
#pragma unroll
        for (int dx = 0; dx < 3; ++dx) {
          float wvv = wv[dy * 3 + dx];
#pragma unroll
          for (int p = 0; p < 4; ++p)
            acc[oc][p] = fmaf(wvv, cwin[dy][p + dx], acc[oc][p]);
        }
      }
    }
  }

  float* ob = out + (size_t)b * 7 * Hn * Wn + h * Wn + w0;
#pragma unroll
  for (int oc = 0; oc < 7; ++oc)
    *(float4*)(ob + (size_t)oc * Hn * Wn) =
        make_float4(acc[oc][0], acc[oc][1], acc[oc][2], acc[oc][3]);
}

extern "C" void kernel_launch(void* const* d_in, const int* in_sizes, int n_in,
                              void* d_out, int out_size, void* d_ws, size_t ws_size,
                              hipStream_t stream) {
  const float* x  = (const float*)d_in[0];
  const float* W1 = (const float*)d_in[1];
  const float* b1 = (const float*)d_in[2];
  const float* W2 = (const float*)d_in[3];
  const float* b2 = (const float*)d_in[4];
  const float* Wm = (const float*)d_in[5];
  const float* bm = (const float*)d_in[6];
  float* out  = (float*)d_out;
  float* comb = (float*)d_ws;  // 8*7*256*256 floats = 14.7 MB

  int nthreads = Bn * Hn * Wn / 4;  // 131072
  sim_kernel<<<nthreads / 256, 256, 0, stream>>>(x, W1, b1, W2, b2, comb);
  mix_kernel<<<nthreads / 256, 256, 0, stream>>>(comb, Wm, bm, out);
}

// Round 2
// 169.550 us; speedup vs baseline: 1.1409x; 1.1409x over previous
//
#include <hip/hip_runtime.h>
#include <math.h>

#define Bn 8
#define Hn 256
#define Wn 256

// Load a 3x6 window (rows h-1..h+1, cols w0-1..w0+4) from a 256x256 plane,
// zero-padded at borders. w0 is a multiple of 4 so the middle 4 cols are one
// aligned float4.
__device__ __forceinline__ void load_win6(const float* __restrict__ plane,
                                          int h, int w0, float win[3][6]) {
#pragma unroll
  for (int r = 0; r < 3; ++r) {
    int hh = h - 1 + r;
    bool okh = (unsigned)hh < (unsigned)Hn;
    const float* row = plane + hh * Wn;
    if (okh) {
      float4 mid = *(const float4*)(row + w0);
      win[r][0] = (w0 > 0) ? row[w0 - 1] : 0.f;
      win[r][1] = mid.x; win[r][2] = mid.y; win[r][3] = mid.z; win[r][4] = mid.w;
      win[r][5] = (w0 + 4 < Wn) ? row[w0 + 4] : 0.f;
    } else {
#pragma unroll
      for (int c = 0; c < 6; ++c) win[r][c] = 0.f;
    }
  }
}

// Kernel A: fused per-neighbor conv1(2->64,3x3)+ReLU -> conv2(64->1,1x1)
// -> sigmoid -> gate neighbor. Writes "combined" (B,7,H,W) into ws.
//
// R2: neighbor dim split across blocks (6 x 512 = 3072 blocks -> 12 blocks/CU
// vs 2 before; R1 showed occupancy 18.5% was the bottleneck, VALU stalled
// ~55% of cycles). Each block stages only its neighbor's weights (5 KB LDS).
// __launch_bounds__(256,4): cap 128 VGPR -> >=16 waves/CU.
__global__ __launch_bounds__(256, 4) void sim_kernel(
    const float* __restrict__ x,   // (8,7,256,256)
    const float* __restrict__ W1,  // (6,64,2,3,3)
    const float* __restrict__ b1,  // (6,64)
    const float* __restrict__ W2,  // (6,1,64,1,1)
    const float* __restrict__ b2,  // (6,1)
    float* __restrict__ comb)      // (8,7,256,256)
{
  __shared__ float4 sw4[64 * 5];

  int n  = blockIdx.x >> 9;     // neighbor 0..5
  int pb = blockIdx.x & 511;    // pixel block 0..511

  // Stage weights for this neighbor. LDS layout per channel c: 20 floats =
  // [wBase(9), wCheck(9), b1, W2]; channel roles pre-swapped for n>=3 so the
  // inner loop is uniform (slot 0..8 always multiplies BASE).
  for (int t = threadIdx.x; t < 64 * 5; t += 256) {
    int c = t / 5, j = t - c * 5;
    int nc = (n << 6) + c;
    float v[4];
#pragma unroll
    for (int e = 0; e < 4; ++e) {
      int kk = 4 * j + e;  // 0..19
      float val;
      if (kk < 18) {
        int i = kk / 9, k = kk - i * 9;
        int isrc = (n < 3) ? i : 1 - i;
        val = W1[nc * 18 + isrc * 9 + k];
      } else if (kk == 18) {
        val = b1[nc];
      } else {
        val = W2[nc];
      }
      v[e] = val;
    }
    sw4[t] = make_float4(v[0], v[1], v[2], v[3]);
  }
  __syncthreads();

  int idx = pb * 256 + threadIdx.x;  // over B*H*W/4 = 131072
  int w0 = (idx & 63) << 2;
  int h  = (idx >> 6) & (Hn - 1);
  int b  = idx >> 14;

  const float* xb = x + (size_t)b * 7 * Hn * Wn;
  float* cb = comb + (size_t)b * 7 * Hn * Wn;

  float bwin[3][6];
  load_win6(xb + 3 * Hn * Wn, h, w0, bwin);

  // combined channel 3 = base (center taps) — written once, by n==0 blocks
  if (n == 0) {
    *(float4*)(cb + 3 * Hn * Wn + h * Wn + w0) =
        make_float4(bwin[1][1], bwin[1][2], bwin[1][3], bwin[1][4]);
  }

  int cc = (n < 3) ? n : n + 1;
  float cwin[3][6];
  load_win6(xb + (size_t)cc * Hn * Wn, h, w0, cwin);

  float s0 = 0.f, s1 = 0.f, s2 = 0.f, s3 = 0.f;
#pragma unroll 2
  for (int c = 0; c < 64; ++c) {
    float4 A = sw4[c * 5 + 0];
    float4 Bq = sw4[c * 5 + 1];
    float4 C = sw4[c * 5 + 2];
    float4 D = sw4[c * 5 + 3];
    float4 E = sw4[c * 5 + 4];
    // wBase taps 0..8, wCheck taps 0..8
    float wb0 = A.x, wb1 = A.y, wb2 = A.z, wb3 = A.w, wb4 = Bq.x;
    float wb5 = Bq.y, wb6 = Bq.z, wb7 = Bq.w, wb8 = C.x;
    float wc0 = C.y, wc1 = C.z, wc2 = C.w, wc3 = D.x, wc4 = D.y;
    float wc5 = D.z, wc6 = D.w, wc7 = E.x, wc8 = E.y;
    float bias = E.z, w2v = E.w;

    float a0 = bias, a1 = bias, a2 = bias, a3 = bias;
#define TAP(WB, WC, dy, dx)                       \
    a0 = fmaf(WB, bwin[dy][0 + dx], a0);          \
    a1 = fmaf(WB, bwin[dy][1 + dx], a1);          \
    a2 = fmaf(WB, bwin[dy][2 + dx], a2);          \
    a3 = fmaf(WB, bwin[dy][3 + dx], a3);          \
    a0 = fmaf(WC, cwin[dy][0 + dx], a0);          \
    a1 = fmaf(WC, cwin[dy][1 + dx], a1);          \
    a2 = fmaf(WC, cwin[dy][2 + dx], a2);          \
    a3 = fmaf(WC, cwin[dy][3 + dx], a3);
    TAP(wb0, wc0, 0, 0) TAP(wb1, wc1, 0, 1) TAP(wb2, wc2, 0, 2)
    TAP(wb3, wc3, 1, 0) TAP(wb4, wc4, 1, 1) TAP(wb5, wc5, 1, 2)
    TAP(wb6, wc6, 2, 0) TAP(wb7, wc7, 2, 1) TAP(wb8, wc8, 2, 2)
#undef TAP
    s0 = fmaf(w2v, fmaxf(a0, 0.f), s0);
    s1 = fmaf(w2v, fmaxf(a1, 0.f), s1);
    s2 = fmaf(w2v, fmaxf(a2, 0.f), s2);
    s3 = fmaf(w2v, fmaxf(a3, 0.f), s3);
  }
  float bb = b2[n];
  float g0 = 1.f / (1.f + expf(-(s0 + bb)));
  float g1 = 1.f / (1.f + expf(-(s1 + bb)));
  float g2 = 1.f / (1.f + expf(-(s2 + bb)));
  float g3 = 1.f / (1.f + expf(-(s3 + bb)));
  *(float4*)(cb + (size_t)cc * Hn * Wn + h * Wn + w0) =
      make_float4(g0 * cwin[1][1], g1 * cwin[1][2],
                  g2 * cwin[1][3], g3 * cwin[1][4]);
}

// Kernel B: final mixing conv (7->7, 3x3, SAME). 4 pixels per thread.
__global__ __launch_bounds__(256, 4) void mix_kernel(
    const float* __restrict__ comb,  // (8,7,256,256)
    const float* __restrict__ Wm,    // (7,7,3,3)
    const float* __restrict__ bm,    // (7,)
    float* __restrict__ out)         // (8,7,256,256)
{
  __shared__ float sW[7 * 7 * 12];  // [oc][ic][12], taps in [0..8]
  __shared__ float sb[7];
  for (int t = threadIdx.x; t < 7 * 7 * 9; t += 256) {
    int oi = t / 9, k = t - oi * 9;
    sW[oi * 12 + k] = Wm[t];
  }
  if (threadIdx.x < 7) sb[threadIdx.x] = bm[threadIdx.x];
  __syncthreads();

  int idx = blockIdx.x * 256 + threadIdx.x;
  int w0 = (idx & 63) << 2;
  int h  = (idx >> 6) & (Hn - 1);
  int b  = idx >> 14;
  const float* cbase = comb + (size_t)b * 7 * Hn * Wn;

  float acc[7][4];
#pragma unroll
  for (int oc = 0; oc < 7; ++oc) {
    float bv = sb[oc];
#pragma unroll
    for (int p = 0; p < 4; ++p) acc[oc][p] = bv;
  }

  for (int ic = 0; ic < 7; ++ic) {
    float cwin[3][6];
    load_win6(cbase + (size_t)ic * Hn * Wn, h, w0, cwin);
#pragma unroll
    for (int oc = 0; oc < 7; ++oc) {
      const float* wp = &sW[(oc * 7 + ic) * 12];
      float4 t1 = *(const float4*)(wp);
      float4 t2 = *(const float4*)(wp + 4);
      float w8 = wp[8];
      float wv[9] = {t1.x, t1.y, t1.z, t1.w, t2.x, t2.y, t2.z, t2.w, w8};
#pragma unroll
      for (int dy = 0; dy < 3; ++dy) {
#pragma unroll
        for (int dx = 0; dx < 3; ++dx) {
          float wvv = wv[dy * 3 + dx];
#pragma unroll
          for (int p = 0; p < 4; ++p)
            acc[oc][p] = fmaf(wvv, cwin[dy][p + dx], acc[oc][p]);
        }
      }
    }
  }

  float* ob = out + (size_t)b * 7 * Hn * Wn + h * Wn + w0;
#pragma unroll
  for (int oc = 0; oc < 7; ++oc)
    *(float4*)(ob + (size_t)oc * Hn * Wn) =
        make_float4(acc[oc][0], acc[oc][1], acc[oc][2], acc[oc][3]);
}

extern "C" void kernel_launch(void* const* d_in, const int* in_sizes, int n_in,
                              void* d_out, int out_size, void* d_ws, size_t ws_size,
                              hipStream_t stream) {
  const float* x  = (const float*)d_in[0];
  const float* W1 = (const float*)d_in[1];
  const float* b1 = (const float*)d_in[2];
  const float* W2 = (const float*)d_in[3];
  const float* b2 = (const float*)d_in[4];
  const float* Wm = (const float*)d_in[5];
  const float* bm = (const float*)d_in[6];
  float* out  = (float*)d_out;
  float* comb = (float*)d_ws;  // 8*7*256*256 floats = 14.7 MB

  int npix4 = Bn * Hn * Wn / 4;  // 131072 threads for pixel work
  sim_kernel<<<6 * (npix4 / 256), 256, 0, stream>>>(x, W1, b1, W2, b2, comb);
  mix_kernel<<<npix4 / 256, 256, 0, stream>>>(comb, Wm, bm, out);
}